// Round 1
// baseline (587.400 us; speedup 1.0000x reference)
//
#include <hip/hip_runtime.h>
#include <cmath>

#define N_   8
#define C_   64
#define H_   160
#define W_   160
#define HW_  25600
#define HH_  80
#define WH_  80

// -------- K1: bilinear resize align_corners=True, 80->160, for high_stage --------
__global__ __launch_bounds__(256) void resize_high_kernel(
    const float* __restrict__ hs, float* __restrict__ high)
{
    int i = blockIdx.x * 256 + threadIdx.x;     // over N*C*H*W = 13,107,200
    int x  = i % W_;
    int t  = i / W_;
    int y  = t % H_;
    int nc = t / H_;                             // n*64 + c
    float sx = (x * 79.0f) / 159.0f;             // exact at endpoints
    float sy = (y * 79.0f) / 159.0f;
    int ix0 = (int)sx, iy0 = (int)sy;
    float fx = sx - (float)ix0, fy = sy - (float)iy0;
    int ix1 = min(ix0 + 1, WH_ - 1), iy1 = min(iy0 + 1, HH_ - 1);
    const float* p = hs + nc * (HH_ * WH_);
    float v00 = p[iy0 * WH_ + ix0], v01 = p[iy0 * WH_ + ix1];
    float v10 = p[iy1 * WH_ + ix0], v11 = p[iy1 * WH_ + ix1];
    float v = (v00 * (1.f - fx) + v01 * fx) * (1.f - fy)
            + (v10 * (1.f - fx) + v11 * fx) * fy;
    high[i] = v;
}

// -------- K1b: resize in_map 80->160 (align_corners=True) + sigmoid --------
__global__ __launch_bounds__(256) void resize_imap_kernel(
    const float* __restrict__ im, float* __restrict__ imap)
{
    int i = blockIdx.x * 256 + threadIdx.x;     // over N*H*W = 204,800
    int x = i % W_;
    int t = i / W_;
    int y = t % H_;
    int n = t / H_;
    float sx = (x * 79.0f) / 159.0f;
    float sy = (y * 79.0f) / 159.0f;
    int ix0 = (int)sx, iy0 = (int)sy;
    float fx = sx - (float)ix0, fy = sy - (float)iy0;
    int ix1 = min(ix0 + 1, WH_ - 1), iy1 = min(iy0 + 1, HH_ - 1);
    const float* p = im + n * (HH_ * WH_);
    float v00 = p[iy0 * WH_ + ix0], v01 = p[iy0 * WH_ + ix1];
    float v10 = p[iy1 * WH_ + ix0], v11 = p[iy1 * WH_ + ix1];
    float v = (v00 * (1.f - fx) + v01 * fx) * (1.f - fy)
            + (v10 * (1.f - fx) + v11 * fx) * fy;
    imap[i] = 1.f / (1.f + expf(-v));
}

// -------- K2: conv1x1 (both branches, 128ci -> 128co) + BN --------
// block = 256 threads handles 64 pixels; wave w owns 32 output channels.
__global__ __launch_bounds__(256) void conv1_bn_kernel(
    const float* __restrict__ low, const float* __restrict__ high,
    const float* __restrict__ w1a, const float* __restrict__ w1b,
    const float* __restrict__ s1, const float* __restrict__ b1,
    const float* __restrict__ m1, const float* __restrict__ v1,
    const float* __restrict__ s2, const float* __restrict__ b2,
    const float* __restrict__ m2, const float* __restrict__ v2,
    float* __restrict__ t1, float* __restrict__ t2)
{
    __shared__ float cat[128][64];
    int tid = threadIdx.x;
    int pbase = blockIdx.x * 64;

    for (int i = tid; i < 128 * 64; i += 256) {
        int ci = i >> 6, px = i & 63;
        int p = pbase + px;
        int n = p / HW_, rem = p % HW_;
        float v;
        if (ci < 64) v = low [(n * 64 + ci)        * HW_ + rem];
        else         v = high[(n * 64 + (ci - 64)) * HW_ + rem];
        cat[ci][px] = v;
    }
    __syncthreads();

    int lane = tid & 63;
    int wid  = __builtin_amdgcn_readfirstlane(tid >> 6);  // wave-uniform
    const float* wsel = (wid < 2) ? w1a : w1b;
    int co_off = (wid & 1) * 32;

    float acc[32];
    #pragma unroll
    for (int j = 0; j < 32; ++j) acc[j] = 0.f;

    for (int c4 = 0; c4 < 32; ++c4) {
        float v0 = cat[c4 * 4 + 0][lane];
        float v1x = cat[c4 * 4 + 1][lane];
        float v2x = cat[c4 * 4 + 2][lane];
        float v3 = cat[c4 * 4 + 3][lane];
        #pragma unroll
        for (int j = 0; j < 32; ++j) {
            const float4 wv = *reinterpret_cast<const float4*>(
                wsel + (co_off + j) * 128 + c4 * 4);   // uniform -> s_load_dwordx4
            acc[j] = fmaf(v0,  wv.x, acc[j]);
            acc[j] = fmaf(v1x, wv.y, acc[j]);
            acc[j] = fmaf(v2x, wv.z, acc[j]);
            acc[j] = fmaf(v3,  wv.w, acc[j]);
        }
    }

    int p = pbase + lane;
    int n = p / HW_, rem = p % HW_;
    const float* ss = (wid < 2) ? s1 : s2;
    const float* bb = (wid < 2) ? b1 : b2;
    const float* mm = (wid < 2) ? m1 : m2;
    const float* vv = (wid < 2) ? v1 : v2;
    float* outp = (wid < 2) ? t1 : t2;
    #pragma unroll
    for (int j = 0; j < 32; ++j) {
        int c = co_off + j;
        float inv  = ss[c] * rsqrtf(vv[c] + 1e-5f);
        float beta = bb[c] - mm[c] * inv;
        outp[(n * 64 + c) * HW_ + rem] = acc[j] * inv + beta;
    }
}

// -------- K3: conv3x3 pad=1, 64ch -> 2ch, both branches --------
__global__ __launch_bounds__(256) void conv3_d_kernel(
    const float* __restrict__ t1, const float* __restrict__ t2,
    const float* __restrict__ w2a, const float* __restrict__ w2b,
    float* __restrict__ d1, float* __restrict__ d2)
{
    __shared__ float wa[1152], wb[1152];
    int tid = threadIdx.x;
    for (int i = tid; i < 1152; i += 256) { wa[i] = w2a[i]; wb[i] = w2b[i]; }
    __syncthreads();

    int p = blockIdx.x * 256 + tid;      // over N*HW = 204,800
    int n = p / HW_, rem = p % HW_;
    int y = rem / W_, x = rem % W_;

    float a10 = 0.f, a11 = 0.f, a20 = 0.f, a21 = 0.f;
    for (int ci = 0; ci < 64; ++ci) {
        const float* p1 = t1 + (n * 64 + ci) * HW_;
        const float* p2 = t2 + (n * 64 + ci) * HW_;
        #pragma unroll
        for (int ky = 0; ky < 3; ++ky) {
            int yy = y + ky - 1;
            float ymsk = ((unsigned)yy < (unsigned)H_) ? 1.f : 0.f;
            int yyc = min(max(yy, 0), H_ - 1);
            #pragma unroll
            for (int kx = 0; kx < 3; ++kx) {
                int xx = x + kx - 1;
                float msk = (((unsigned)xx < (unsigned)W_) ? 1.f : 0.f) * ymsk;
                int xxc = min(max(xx, 0), W_ - 1);
                float v1d = p1[yyc * W_ + xxc] * msk;
                float v2d = p2[yyc * W_ + xxc] * msk;
                int wi = ci * 9 + ky * 3 + kx;
                a10 = fmaf(v1d, wa[wi],       a10);
                a11 = fmaf(v1d, wa[576 + wi], a11);
                a20 = fmaf(v2d, wb[wi],       a20);
                a21 = fmaf(v2d, wb[576 + wi], a21);
            }
        }
    }
    d1[(n * 2 + 0) * HW_ + rem] = a10;
    d1[(n * 2 + 1) * HW_ + rem] = a11;
    d2[(n * 2 + 0) * HW_ + rem] = a20;
    d2[(n * 2 + 1) * HW_ + rem] = a21;
}

// -------- grid_sample bilinear, align_corners=False, zeros padding --------
__device__ __forceinline__ float gs_sample(const float* __restrict__ img,
                                           float px, float py)
{
    float x0f = floorf(px), y0f = floorf(py);
    float wx1 = px - x0f,  wy1 = py - y0f;
    float wx0 = 1.f - wx1, wy0 = 1.f - wy1;
    int x0 = (int)x0f, y0 = (int)y0f;
    float mx0 = ((unsigned)x0       < (unsigned)W_) ? 1.f : 0.f;
    float mx1 = ((unsigned)(x0 + 1) < (unsigned)W_) ? 1.f : 0.f;
    float my0 = ((unsigned)y0       < (unsigned)H_) ? 1.f : 0.f;
    float my1 = ((unsigned)(y0 + 1) < (unsigned)H_) ? 1.f : 0.f;
    int x0c = min(max(x0, 0), W_ - 1), x1c = min(max(x0 + 1, 0), W_ - 1);
    int y0c = min(max(y0, 0), H_ - 1), y1c = min(max(y0 + 1, 0), H_ - 1);
    float v00 = img[y0c * W_ + x0c] * (my0 * mx0);
    float v01 = img[y0c * W_ + x1c] * (my0 * mx1);
    float v10 = img[y1c * W_ + x0c] * (my1 * mx0);
    float v11 = img[y1c * W_ + x1c] * (my1 * mx1);
    return (v00 * wx0 + v01 * wx1) * wy0 + (v10 * wx0 + v11 * wx1) * wy1;
}

// -------- K4: warp(high,d1) + warp(low,d2), combine with imap -> f --------
__global__ __launch_bounds__(256) void warp_combine_kernel(
    const float* __restrict__ low, const float* __restrict__ high,
    const float* __restrict__ d1, const float* __restrict__ d2,
    const float* __restrict__ imap, const float* __restrict__ gamma,
    float* __restrict__ f)
{
    int i = blockIdx.x * 256 + threadIdx.x;   // over N*C*HW
    int rem = i % HW_;
    int t = i / HW_;
    int c = t % C_;
    int n = t / C_;
    int x = rem % W_, y = rem / W_;

    float gx = -1.f + x * (2.f / 159.f);
    float gy = -1.f + y * (2.f / 159.f);

    int db = n * 2 * HW_ + rem;
    float g1x = gx + d1[db]       * (1.f / 160.f);
    float g1y = gy + d1[db + HW_] * (1.f / 160.f);
    float g2x = gx + d2[db]       * (1.f / 160.f);
    float g2y = gy + d2[db + HW_] * (1.f / 160.f);

    float p1x = (g1x + 1.f) * 80.f - 0.5f;
    float p1y = (g1y + 1.f) * 80.f - 0.5f;
    float p2x = (g2x + 1.f) * 80.f - 0.5f;
    float p2y = (g2y + 1.f) * 80.f - 0.5f;

    const float* himg = high + (n * C_ + c) * HW_;
    const float* limg = low  + (n * C_ + c) * HW_;
    float hi = gs_sample(himg, p1x, p1y);
    float lo = gs_sample(limg, p2x, p2y);
    float hsv = hi + lo;
    float imv = imap[n * HW_ + rem];
    f[i] = hsv * (1.f + gamma[0] * imv);
}

// -------- K5: conv3x3 pad=1, 64ch -> 1ch + bias --------
__global__ __launch_bounds__(256) void out_conv_kernel(
    const float* __restrict__ f, const float* __restrict__ ow,
    const float* __restrict__ ob, float* __restrict__ o)
{
    __shared__ float w[576];
    int tid = threadIdx.x;
    for (int i = tid; i < 576; i += 256) w[i] = ow[i];
    __syncthreads();

    int p = blockIdx.x * 256 + tid;      // over N*HW
    int n = p / HW_, rem = p % HW_;
    int y = rem / W_, x = rem % W_;

    float acc = 0.f;
    for (int ci = 0; ci < 64; ++ci) {
        const float* pf = f + (n * C_ + ci) * HW_;
        #pragma unroll
        for (int ky = 0; ky < 3; ++ky) {
            int yy = y + ky - 1;
            float ymsk = ((unsigned)yy < (unsigned)H_) ? 1.f : 0.f;
            int yyc = min(max(yy, 0), H_ - 1);
            #pragma unroll
            for (int kx = 0; kx < 3; ++kx) {
                int xx = x + kx - 1;
                float msk = (((unsigned)xx < (unsigned)W_) ? 1.f : 0.f) * ymsk;
                int xxc = min(max(xx, 0), W_ - 1);
                acc = fmaf(pf[yyc * W_ + xxc] * msk, w[ci * 9 + ky * 3 + kx], acc);
            }
        }
    }
    o[p] = acc + ob[0];
}

extern "C" void kernel_launch(void* const* d_in, const int* in_sizes, int n_in,
                              void* d_out, int out_size, void* d_ws, size_t ws_size,
                              hipStream_t stream) {
    const float* low    = (const float*)d_in[0];
    const float* hsin   = (const float*)d_in[1];
    const float* imin   = (const float*)d_in[2];
    const float* dg1_w1 = (const float*)d_in[3];
    const float* dg1_s  = (const float*)d_in[4];
    const float* dg1_b  = (const float*)d_in[5];
    const float* dg1_m  = (const float*)d_in[6];
    const float* dg1_v  = (const float*)d_in[7];
    const float* dg1_w2 = (const float*)d_in[8];
    const float* dg2_w1 = (const float*)d_in[9];
    const float* dg2_s  = (const float*)d_in[10];
    const float* dg2_b  = (const float*)d_in[11];
    const float* dg2_m  = (const float*)d_in[12];
    const float* dg2_v  = (const float*)d_in[13];
    const float* dg2_w2 = (const float*)d_in[14];
    const float* gamma  = (const float*)d_in[15];
    const float* out_w  = (const float*)d_in[16];
    const float* out_b  = (const float*)d_in[17];

    const int FSZ = N_ * C_ * HW_;        // 13,107,200
    const int PSZ = N_ * HW_;             // 204,800

    float* ws   = (float*)d_ws;
    float* high = ws;                     // FSZ
    float* imap = high + FSZ;             // PSZ
    float* t2   = imap + PSZ;             // FSZ
    float* d1   = t2 + FSZ;               // 2*PSZ
    float* d2   = d1 + 2 * PSZ;           // 2*PSZ

    float* fout = (float*)d_out;          // FSZ  (output 0)
    float* t1   = fout;                   // staged in d_out, dead before K4 writes f
    float* oout = fout + FSZ;             // PSZ  (output 1)

    resize_high_kernel<<<FSZ / 256, 256, 0, stream>>>(hsin, high);
    resize_imap_kernel<<<PSZ / 256, 256, 0, stream>>>(imin, imap);
    conv1_bn_kernel<<<PSZ / 64, 256, 0, stream>>>(
        low, high, dg1_w1, dg2_w1,
        dg1_s, dg1_b, dg1_m, dg1_v,
        dg2_s, dg2_b, dg2_m, dg2_v, t1, t2);
    conv3_d_kernel<<<PSZ / 256, 256, 0, stream>>>(t1, t2, dg1_w2, dg2_w2, d1, d2);
    warp_combine_kernel<<<FSZ / 256, 256, 0, stream>>>(
        low, high, d1, d2, imap, gamma, fout);
    out_conv_kernel<<<PSZ / 256, 256, 0, stream>>>(fout, out_w, out_b, oout);
}